// Round 1
// baseline (306.271 us; speedup 1.0000x reference)
//
#include <hip/hip_runtime.h>
#include <hip/hip_bf16.h>

#define DEVI __device__ __forceinline__

typedef __hip_bfloat16 bf16;
typedef __attribute__((ext_vector_type(8))) __bf16 bf16x8;   // MFMA A/B operand (4 VGPRs)
typedef __attribute__((ext_vector_type(4))) float f32x4;     // MFMA C/D
typedef __attribute__((ext_vector_type(4))) short short4v;
typedef __attribute__((ext_vector_type(8))) short short8v;

// B=2, L=2048, DM=1024, H=16, DK=DV=64

DEVI short bfbits(float f) { bf16 h = __float2bfloat16(f); return *(short*)&h; }

DEVI void gl16(const void* g, void* l) {
  __builtin_amdgcn_global_load_lds((const __attribute__((address_space(1))) void*)g,
                                   (__attribute__((address_space(3))) void*)l, 16, 0, 0);
}

DEVI f32x4 MF(bf16x8 a, bf16x8 b, f32x4 c) {
  return __builtin_amdgcn_mfma_f32_16x16x32_bf16(a, b, c, 0, 0, 0);
}

// ---------- kernel 1: Q,K,V fp32 -> bf16 ----------
__global__ __launch_bounds__(256) void k_cvt_qkv(
    const float* __restrict__ Q, const float* __restrict__ K, const float* __restrict__ V,
    bf16* __restrict__ Qb, bf16* __restrict__ Kb, bf16* __restrict__ Vb) {
  const float* s = blockIdx.y == 0 ? Q : (blockIdx.y == 1 ? K : V);
  bf16* d = blockIdx.y == 0 ? Qb : (blockIdx.y == 1 ? Kb : Vb);
  int i = (blockIdx.x * 256 + threadIdx.x) * 4;
  float4 v = *(const float4*)(s + i);
  short4v o;
  o[0] = bfbits(v.x); o[1] = bfbits(v.y); o[2] = bfbits(v.z); o[3] = bfbits(v.w);
  *(short4v*)(d + i) = o;
}

// ---------- kernel 2: weight transpose + cvt ----------
// z<3: Wq/Wk/Wv [H][1024][64] -> WT[h*64+j][m]  (B^T layout [N][K])
// z=3: Wo [1024][1024]        -> WoT[d][hv]
__global__ __launch_bounds__(256) void k_prep_w(
    const float* __restrict__ Wq, const float* __restrict__ Wk, const float* __restrict__ Wv,
    const float* __restrict__ Wo,
    bf16* __restrict__ WqT, bf16* __restrict__ WkT, bf16* __restrict__ WvT,
    bf16* __restrict__ WoT) {
  __shared__ float t[64][65];
  const int z = blockIdx.z;
  const float* in; bf16* out; int ldin, ldout;
  if (z < 3) {
    const float* W = z == 0 ? Wq : (z == 1 ? Wk : Wv);
    bf16* O = z == 0 ? WqT : (z == 1 ? WkT : WvT);
    const int hh = blockIdx.y, m0 = blockIdx.x * 64;
    in = W + hh * 65536 + m0 * 64; ldin = 64;
    out = O + hh * 65536 + m0;     ldout = 1024;
  } else {
    const int r0 = blockIdx.x * 64, c0 = blockIdx.y * 64;
    in = Wo + r0 * 1024 + c0; ldin = 1024;
    out = WoT + c0 * 1024 + r0; ldout = 1024;
  }
  const int tx = threadIdx.x & 63, ty = threadIdx.x >> 6;
  for (int r = ty; r < 64; r += 4) t[r][tx] = in[r * ldin + tx];
  __syncthreads();
  for (int c = ty; c < 64; c += 4) out[c * ldout + tx] = __float2bfloat16(t[tx][c]);
}

// ---------- kernel 3: projections. C[4096][1024] = A[4096][1024] @ BT^T + bias ----------
// z=0: Qp (natural), z=1: Kp (natural), z=2: Vp written TRANSPOSED per (b,h): VpT[(bh*64+v)][s]
__global__ __launch_bounds__(256) void k_proj_gemm(
    const bf16* __restrict__ Qb, const bf16* __restrict__ Kb, const bf16* __restrict__ Vb,
    const bf16* __restrict__ WqT, const bf16* __restrict__ WkT, const bf16* __restrict__ WvT,
    const float* __restrict__ bq, const float* __restrict__ bk, const float* __restrict__ bv,
    bf16* __restrict__ Qp, bf16* __restrict__ Kp, bf16* __restrict__ VpT) {
  __shared__ bf16 As[128 * 64], Bs[128 * 64];
  const int z = blockIdx.z;
  const bf16* A  = z == 0 ? Qb : (z == 1 ? Kb : Vb);
  const bf16* BT = z == 0 ? WqT : (z == 1 ? WkT : WvT);
  const float* bias = z == 0 ? bq : (z == 1 ? bk : bv);
  const int row0 = blockIdx.x * 128, col0 = blockIdx.y * 128;
  const int tid = threadIdx.x, lane = tid & 63, wave = tid >> 6;
  const int wq = wave >> 1, wn = wave & 1;
  f32x4 acc[4][4];
#pragma unroll
  for (int i = 0; i < 4; ++i)
#pragma unroll
    for (int j = 0; j < 4; ++j) acc[i][j] = (f32x4)0.0f;

  for (int k0 = 0; k0 < 1024; k0 += 64) {
#pragma unroll
    for (int it = 0; it < 4; ++it) {
      int boff = (it * 4 + wave) * 1024 + lane * 16;
      int r = boff >> 7, cb = boff & 127;
      gl16((const char*)A  + (size_t)(row0 + r) * 2048 + k0 * 2 + cb, (char*)As + boff);
      gl16((const char*)BT + (size_t)(col0 + r) * 2048 + k0 * 2 + cb, (char*)Bs + boff);
    }
    __syncthreads();
#pragma unroll
    for (int ks = 0; ks < 2; ++ks) {
      bf16x8 a[4], b[4];
#pragma unroll
      for (int i = 0; i < 4; ++i)
        a[i] = *(const bf16x8*)&As[(wq * 64 + i * 16 + (lane & 15)) * 64 + ks * 32 + (lane >> 4) * 8];
#pragma unroll
      for (int j = 0; j < 4; ++j)
        b[j] = *(const bf16x8*)&Bs[(wn * 64 + j * 16 + (lane & 15)) * 64 + ks * 32 + (lane >> 4) * 8];
#pragma unroll
      for (int i = 0; i < 4; ++i)
#pragma unroll
        for (int j = 0; j < 4; ++j) acc[i][j] = MF(a[i], b[j], acc[i][j]);
    }
    __syncthreads();
  }

  if (z < 2) {
    bf16* C = z == 0 ? Qp : Kp;
#pragma unroll
    for (int i = 0; i < 4; ++i)
#pragma unroll
      for (int j = 0; j < 4; ++j) {
        int col = col0 + wn * 64 + j * 16 + (lane & 15);
        float bb = bias[col];
#pragma unroll
        for (int r = 0; r < 4; ++r) {
          int row = row0 + wq * 64 + i * 16 + (lane >> 4) * 4 + r;
          C[row * 1024 + col] = __float2bfloat16(acc[i][j][r] + bb);
        }
      }
  } else {
    const int b = row0 >> 11, lr = row0 & 2047;
#pragma unroll
    for (int i = 0; i < 4; ++i)
#pragma unroll
      for (int j = 0; j < 4; ++j) {
        int n = col0 + wn * 64 + j * 16 + (lane & 15);
        float bb = bias[n];
        int s0 = lr + wq * 64 + i * 16 + (lane >> 4) * 4;
        short4v o;
#pragma unroll
        for (int r = 0; r < 4; ++r) o[r] = bfbits(acc[i][j][r] + bb);
        *(short4v*)&VpT[((b * 16 + (n >> 6)) * 64 + (n & 63)) * 2048 + s0] = o;
      }
  }
}

// ---------- kernel 4: column-softmax stats: lc[bh][s] = -log(sum_q exp(S[q,s]/8)) ----------
// computes S^T tiles: A-frags from Kp rows (s), B-frags from Qp rows (q)
__global__ __launch_bounds__(256) void k_stats(
    const bf16* __restrict__ Qp, const bf16* __restrict__ Kp, float* __restrict__ lc) {
  __shared__ bf16 Ks[128 * 64], Qs[64 * 64];
  const int s0 = blockIdx.x * 128, bh = blockIdx.y;
  const int b = bh >> 4, h = bh & 15;
  const char* Qrow = (const char*)(Qp + (b * 2048) * 1024 + h * 64);
  const char* Krow = (const char*)(Kp + (b * 2048) * 1024 + h * 64);
  const int tid = threadIdx.x, lane = tid & 63, wave = tid >> 6;
#pragma unroll
  for (int it = 0; it < 4; ++it) {
    int boff = (it * 4 + wave) * 1024 + lane * 16;
    int r = boff >> 7, cb = boff & 127;
    gl16(Krow + (size_t)(s0 + r) * 2048 + cb, (char*)Ks + boff);
  }
  __syncthreads();
  bf16x8 afr[2][2];  // wave's 32 s-rows, hoisted
#pragma unroll
  for (int sf = 0; sf < 2; ++sf)
#pragma unroll
    for (int ks = 0; ks < 2; ++ks)
      afr[sf][ks] = *(const bf16x8*)&Ks[(wave * 32 + sf * 16 + (lane & 15)) * 64 + ks * 32 + (lane >> 4) * 8];
  float zr[2][4] = {{0.f, 0.f, 0.f, 0.f}, {0.f, 0.f, 0.f, 0.f}};

  for (int q0 = 0; q0 < 2048; q0 += 64) {
    __syncthreads();
#pragma unroll
    for (int it = 0; it < 2; ++it) {
      int boff = (it * 4 + wave) * 1024 + lane * 16;
      int r = boff >> 7, cb = boff & 127;
      gl16(Qrow + (size_t)(q0 + r) * 2048 + cb, (char*)Qs + boff);
    }
    __syncthreads();
    f32x4 acc[2][4];
#pragma unroll
    for (int sf = 0; sf < 2; ++sf)
#pragma unroll
      for (int qf = 0; qf < 4; ++qf) acc[sf][qf] = (f32x4)0.0f;
#pragma unroll
    for (int ks = 0; ks < 2; ++ks) {
      bf16x8 bfr[4];
#pragma unroll
      for (int qf = 0; qf < 4; ++qf)
        bfr[qf] = *(const bf16x8*)&Qs[(qf * 16 + (lane & 15)) * 64 + ks * 32 + (lane >> 4) * 8];
#pragma unroll
      for (int sf = 0; sf < 2; ++sf)
#pragma unroll
        for (int qf = 0; qf < 4; ++qf) acc[sf][qf] = MF(afr[sf][ks], bfr[qf], acc[sf][qf]);
    }
    // acc[sf][qf]: rows s = s0+wave*32+sf*16+4*(lane>>4)+r, col q = q0+qf*16+(lane&15)
#pragma unroll
    for (int sf = 0; sf < 2; ++sf)
#pragma unroll
      for (int qf = 0; qf < 4; ++qf)
#pragma unroll
        for (int r = 0; r < 4; ++r) zr[sf][r] += __expf(acc[sf][qf][r] * 0.125f);
  }
  // reduce over the 16-lane (lane&15) q-partition
#pragma unroll
  for (int m = 1; m <= 8; m <<= 1)
#pragma unroll
    for (int sf = 0; sf < 2; ++sf)
#pragma unroll
      for (int r = 0; r < 4; ++r) zr[sf][r] += __shfl_xor(zr[sf][r], m);
  if ((lane & 15) == 0) {
#pragma unroll
    for (int sf = 0; sf < 2; ++sf)
#pragma unroll
      for (int r = 0; r < 4; ++r)
        lc[bh * 2048 + s0 + wave * 32 + sf * 16 + (lane >> 4) * 4 + r] = -__logf(zr[sf][r]);
  }
}

// ---------- kernel 5: wV[q,v] = sum_s exp(S/8 + lc_s) * Vp[s,v] ----------
__global__ __launch_bounds__(256) void k_attn_pv(
    const bf16* __restrict__ Qp, const bf16* __restrict__ Kp, const bf16* __restrict__ VpT,
    const float* __restrict__ lc, bf16* __restrict__ wV) {
  __shared__ bf16 Qs[128 * 64];   // 16KB, staged once
  __shared__ bf16 Ks[64 * 64];    // 8KB per s-chunk
  __shared__ bf16 Vs[64 * 64];    // 8KB per s-chunk (VpT rows: [v][s])
  __shared__ bf16 Ps[128 * 72];   // 18KB padded P tile [q][s]
  __shared__ float lcs[64];
  const int q0 = blockIdx.x * 128, bh = blockIdx.y;
  const int b = bh >> 4, h = bh & 15;
  const char* Qrow = (const char*)(Qp + (b * 2048) * 1024 + h * 64);
  const char* Krow = (const char*)(Kp + (b * 2048) * 1024 + h * 64);
  const char* Vrow = (const char*)(VpT + bh * 64 * 2048);
  const float* lcb = lc + bh * 2048;
  const int tid = threadIdx.x, lane = tid & 63, wave = tid >> 6;

#pragma unroll
  for (int it = 0; it < 4; ++it) {
    int boff = (it * 4 + wave) * 1024 + lane * 16;
    int r = boff >> 7, cb = boff & 127;
    gl16(Qrow + (size_t)(q0 + r) * 2048 + cb, (char*)Qs + boff);
  }
  __syncthreads();
  bf16x8 aq[2][2];  // wave's 32 q-rows, hoisted
#pragma unroll
  for (int qf = 0; qf < 2; ++qf)
#pragma unroll
    for (int ks = 0; ks < 2; ++ks)
      aq[qf][ks] = *(const bf16x8*)&Qs[(wave * 32 + qf * 16 + (lane & 15)) * 64 + ks * 32 + (lane >> 4) * 8];

  f32x4 acco[2][4];
#pragma unroll
  for (int qf = 0; qf < 2; ++qf)
#pragma unroll
    for (int vf = 0; vf < 4; ++vf) acco[qf][vf] = (f32x4)0.0f;

  for (int sc = 0; sc < 2048; sc += 64) {
    __syncthreads();
#pragma unroll
    for (int it = 0; it < 2; ++it) {
      int boff = (it * 4 + wave) * 1024 + lane * 16;
      int r = boff >> 7, cb = boff & 127;
      gl16(Krow + (size_t)(sc + r) * 2048 + cb, (char*)Ks + boff);
      gl16(Vrow + (size_t)r * 4096 + sc * 2 + cb, (char*)Vs + boff);
    }
    if (tid < 64) lcs[tid] = lcb[sc + tid];
    __syncthreads();

    f32x4 sacc[2][4];
#pragma unroll
    for (int qf = 0; qf < 2; ++qf)
#pragma unroll
      for (int sf = 0; sf < 4; ++sf) sacc[qf][sf] = (f32x4)0.0f;
#pragma unroll
    for (int ks = 0; ks < 2; ++ks) {
      bf16x8 bk_[4];
#pragma unroll
      for (int sf = 0; sf < 4; ++sf)
        bk_[sf] = *(const bf16x8*)&Ks[(sf * 16 + (lane & 15)) * 64 + ks * 32 + (lane >> 4) * 8];
#pragma unroll
      for (int qf = 0; qf < 2; ++qf)
#pragma unroll
        for (int sf = 0; sf < 4; ++sf) sacc[qf][sf] = MF(aq[qf][ks], bk_[sf], sacc[qf][sf]);
    }
    // P = exp(S/8 + lc_s) -> Ps (each wave touches only its own 32 q-rows; no barrier needed)
#pragma unroll
    for (int qf = 0; qf < 2; ++qf)
#pragma unroll
      for (int sf = 0; sf < 4; ++sf) {
        int sl = sf * 16 + (lane & 15);
        float lcv = lcs[sl];
#pragma unroll
        for (int r = 0; r < 4; ++r) {
          float p = __expf(sacc[qf][sf][r] * 0.125f + lcv);
          Ps[(wave * 32 + qf * 16 + (lane >> 4) * 4 + r) * 72 + sl] = __float2bfloat16(p);
        }
      }
    // PV accumulate
#pragma unroll
    for (int ks = 0; ks < 2; ++ks) {
      bf16x8 pa[2], pb[4];
#pragma unroll
      for (int qf = 0; qf < 2; ++qf)
        pa[qf] = *(const bf16x8*)&Ps[(wave * 32 + qf * 16 + (lane & 15)) * 72 + ks * 32 + (lane >> 4) * 8];
#pragma unroll
      for (int vf = 0; vf < 4; ++vf)
        pb[vf] = *(const bf16x8*)&Vs[(vf * 16 + (lane & 15)) * 64 + ks * 32 + (lane >> 4) * 8];
#pragma unroll
      for (int qf = 0; qf < 2; ++qf)
#pragma unroll
        for (int vf = 0; vf < 4; ++vf) acco[qf][vf] = MF(pa[qf], pb[vf], acco[qf][vf]);
    }
  }
  // bounce accumulator through Ps for coalesced bf16 output
#pragma unroll
  for (int qf = 0; qf < 2; ++qf)
#pragma unroll
    for (int vf = 0; vf < 4; ++vf) {
      int v = vf * 16 + (lane & 15);
#pragma unroll
      for (int r = 0; r < 4; ++r)
        Ps[(wave * 32 + qf * 16 + (lane >> 4) * 4 + r) * 72 + v] = __float2bfloat16(acco[qf][vf][r]);
    }
  __syncthreads();
  {
    int r = tid >> 1, p = tid & 1;
    char* dst = (char*)(wV + (bh * 2048 + q0 + r) * 64 + p * 32);
#pragma unroll
    for (int i = 0; i < 4; ++i) {
      short8v x = *(const short8v*)&Ps[r * 72 + p * 32 + i * 8];
      *(short8v*)(dst + i * 16) = x;
    }
  }
}

// ---------- kernel 6: out[4096][1024] = wV_cat @ Wo + bo (fp32 out) ----------
__global__ __launch_bounds__(256) void k_out_gemm(
    const bf16* __restrict__ wV, const bf16* __restrict__ WoT, const float* __restrict__ bo,
    float* __restrict__ out) {
  __shared__ bf16 As[128 * 64], Bs[128 * 64];
  const int row0 = blockIdx.x * 128, col0 = blockIdx.y * 128;
  const int tid = threadIdx.x, lane = tid & 63, wave = tid >> 6;
  const int wq = wave >> 1, wn = wave & 1;
  const int b = row0 >> 11, lr = row0 & 2047;
  f32x4 acc[4][4];
#pragma unroll
  for (int i = 0; i < 4; ++i)
#pragma unroll
    for (int j = 0; j < 4; ++j) acc[i][j] = (f32x4)0.0f;

  for (int k0 = 0; k0 < 1024; k0 += 64) {
    // k-tile of 64 == one head's 64 v-cols: contiguous 16KB slice of wV
    const char* Abase = (const char*)(wV + ((b * 16 + (k0 >> 6)) * 2048 + lr) * 64);
#pragma unroll
    for (int it = 0; it < 4; ++it) {
      int boff = (it * 4 + wave) * 1024 + lane * 16;
      int r = boff >> 7, cb = boff & 127;
      gl16(Abase + boff, (char*)As + boff);
      gl16((const char*)WoT + (size_t)(col0 + r) * 2048 + k0 * 2 + cb, (char*)Bs + boff);
    }
    __syncthreads();
#pragma unroll
    for (int ks = 0; ks < 2; ++ks) {
      bf16x8 a[4], bb[4];
#pragma unroll
      for (int i = 0; i < 4; ++i)
        a[i] = *(const bf16x8*)&As[(wq * 64 + i * 16 + (lane & 15)) * 64 + ks * 32 + (lane >> 4) * 8];
#pragma unroll
      for (int j = 0; j < 4; ++j)
        bb[j] = *(const bf16x8*)&Bs[(wn * 64 + j * 16 + (lane & 15)) * 64 + ks * 32 + (lane >> 4) * 8];
#pragma unroll
      for (int i = 0; i < 4; ++i)
#pragma unroll
        for (int j = 0; j < 4; ++j) acc[i][j] = MF(a[i], bb[j], acc[i][j]);
    }
    __syncthreads();
  }
#pragma unroll
  for (int i = 0; i < 4; ++i)
#pragma unroll
    for (int j = 0; j < 4; ++j) {
      int col = col0 + wn * 64 + j * 16 + (lane & 15);
      float bb = bo[col];
#pragma unroll
      for (int r = 0; r < 4; ++r) {
        int row = row0 + wq * 64 + i * 16 + (lane >> 4) * 4 + r;
        out[row * 1024 + col] = acc[i][j][r] + bb;
      }
    }
}

extern "C" void kernel_launch(void* const* d_in, const int* in_sizes, int n_in,
                              void* d_out, int out_size, void* d_ws, size_t ws_size,
                              hipStream_t stream) {
  (void)in_sizes; (void)n_in; (void)out_size; (void)ws_size;
  const float* Q  = (const float*)d_in[0];
  const float* K  = (const float*)d_in[1];
  const float* V  = (const float*)d_in[2];
  const float* Wq = (const float*)d_in[3];
  const float* bq = (const float*)d_in[4];
  const float* Wk = (const float*)d_in[5];
  const float* bk = (const float*)d_in[6];
  const float* Wv = (const float*)d_in[7];
  const float* bv = (const float*)d_in[8];
  const float* Wo = (const float*)d_in[9];
  const float* bo = (const float*)d_in[10];

  char* ws = (char*)d_ws;
  bf16* Qb  = (bf16*)(ws);                     // 8 MB  [4096][1024]
  bf16* Kb  = (bf16*)(ws + (8u  << 20));       // 8 MB
  bf16* Vb  = (bf16*)(ws + (16u << 20));       // 8 MB
  bf16* WqT = (bf16*)(ws + (24u << 20));       // 2 MB  [1024 n][1024 m]
  bf16* WkT = (bf16*)(ws + (26u << 20));       // 2 MB
  bf16* WvT = (bf16*)(ws + (28u << 20));       // 2 MB
  bf16* WoT = (bf16*)(ws + (30u << 20));       // 2 MB
  bf16* Qp  = (bf16*)(ws + (32u << 20));       // 8 MB  [4096][1024] (n = h*64+k)
  bf16* Kp  = (bf16*)(ws + (40u << 20));       // 8 MB
  bf16* VpT = (bf16*)(ws + (48u << 20));       // 8 MB  [(bh*64+v)][2048 s]
  bf16* wVn = (bf16*)(ws + (56u << 20));       // 8 MB  [(bh*2048+l)][64 v]
  float* lc = (float*)(ws + (64u << 20));      // 256 KB [bh][2048]

  k_cvt_qkv <<<dim3(4096, 3), 256, 0, stream>>>(Q, K, V, Qb, Kb, Vb);
  k_prep_w  <<<dim3(16, 16, 4), 256, 0, stream>>>(Wq, Wk, Wv, Wo, WqT, WkT, WvT, WoT);
  k_proj_gemm<<<dim3(32, 8, 3), 256, 0, stream>>>(Qb, Kb, Vb, WqT, WkT, WvT, bq, bk, bv, Qp, Kp, VpT);
  k_stats   <<<dim3(16, 32), 256, 0, stream>>>(Qp, Kp, lc);
  k_attn_pv <<<dim3(16, 32), 256, 0, stream>>>(Qp, Kp, VpT, lc, wVn);
  k_out_gemm<<<dim3(32, 8), 256, 0, stream>>>(wVn, WoT, bo, (float*)d_out);
}

// Round 2
// 262.524 us; speedup vs baseline: 1.1666x; 1.1666x over previous
//
#include <hip/hip_runtime.h>
#include <hip/hip_bf16.h>

#define DEVI __device__ __forceinline__

typedef __hip_bfloat16 bf16;
typedef __attribute__((ext_vector_type(8))) __bf16 bf16x8;   // MFMA A/B operand (4 VGPRs)
typedef __attribute__((ext_vector_type(4))) float f32x4;     // MFMA C/D
typedef __attribute__((ext_vector_type(4))) short short4v;
typedef __attribute__((ext_vector_type(8))) short short8v;

// B=2, L=2048, DM=1024, H=16, DK=DV=64

DEVI short bfbits(float f) { bf16 h = __float2bfloat16(f); return *(short*)&h; }
DEVI float b2f(short s) { union { float f; unsigned u; } c; c.u = ((unsigned)(unsigned short)s) << 16; return c.f; }

DEVI void gl16(const void* g, void* l) {
  __builtin_amdgcn_global_load_lds((const __attribute__((address_space(1))) void*)g,
                                   (__attribute__((address_space(3))) void*)l, 16, 0, 0);
}

DEVI f32x4 MF(bf16x8 a, bf16x8 b, f32x4 c) {
  return __builtin_amdgcn_mfma_f32_16x16x32_bf16(a, b, c, 0, 0, 0);
}

// XOR swizzle for 64-bf16 (128B) pitch LDS tiles.
// element index for (row, elem col); XOR spreads the 16B slot by row&7.
DEVI int swzE(int row, int ec) { return row * 64 + (ec ^ ((row & 7) << 3)); }
// staging: for LDS linear byte offset boff, the GLOBAL source byte-col within the row.
DEVI int srcC(int boff) { return (boff & 127) ^ (((boff >> 7) & 7) << 4); }

// ---------- kernel 1: Q,K,V fp32 -> bf16 ----------
__global__ __launch_bounds__(256) void k_cvt_qkv(
    const float* __restrict__ Q, const float* __restrict__ K, const float* __restrict__ V,
    bf16* __restrict__ Qb, bf16* __restrict__ Kb, bf16* __restrict__ Vb) {
  const float* s = blockIdx.y == 0 ? Q : (blockIdx.y == 1 ? K : V);
  bf16* d = blockIdx.y == 0 ? Qb : (blockIdx.y == 1 ? Kb : Vb);
  int i = (blockIdx.x * 256 + threadIdx.x) * 4;
  float4 v = *(const float4*)(s + i);
  short4v o;
  o[0] = bfbits(v.x); o[1] = bfbits(v.y); o[2] = bfbits(v.z); o[3] = bfbits(v.w);
  *(short4v*)(d + i) = o;
}

// ---------- kernel 2: weight transpose + cvt ----------
__global__ __launch_bounds__(256) void k_prep_w(
    const float* __restrict__ Wq, const float* __restrict__ Wk, const float* __restrict__ Wv,
    const float* __restrict__ Wo,
    bf16* __restrict__ WqT, bf16* __restrict__ WkT, bf16* __restrict__ WvT,
    bf16* __restrict__ WoT) {
  __shared__ float t[64][65];
  const int z = blockIdx.z;
  const float* in; bf16* out; int ldin, ldout;
  if (z < 3) {
    const float* W = z == 0 ? Wq : (z == 1 ? Wk : Wv);
    bf16* O = z == 0 ? WqT : (z == 1 ? WkT : WvT);
    const int hh = blockIdx.y, m0 = blockIdx.x * 64;
    in = W + hh * 65536 + m0 * 64; ldin = 64;
    out = O + hh * 65536 + m0;     ldout = 1024;
  } else {
    const int r0 = blockIdx.x * 64, c0 = blockIdx.y * 64;
    in = Wo + r0 * 1024 + c0; ldin = 1024;
    out = WoT + c0 * 1024 + r0; ldout = 1024;
  }
  const int tx = threadIdx.x & 63, ty = threadIdx.x >> 6;
  for (int r = ty; r < 64; r += 4) t[r][tx] = in[r * ldin + tx];
  __syncthreads();
  for (int c = ty; c < 64; c += 4) out[c * ldout + tx] = __float2bfloat16(t[tx][c]);
}

// ---------- kernel 3: projections ----------
// z=0: Qp = (Q@Wq + bq) * 0.125  (1/sqrt(dk) folded in)
// z=1: Kp natural, z=2: Vp written TRANSPOSED per (b,h): VpT[(bh*64+v)][s] via LDS transpose
__global__ __launch_bounds__(256) void k_proj_gemm(
    const bf16* __restrict__ Qb, const bf16* __restrict__ Kb, const bf16* __restrict__ Vb,
    const bf16* __restrict__ WqT, const bf16* __restrict__ WkT, const bf16* __restrict__ WvT,
    const float* __restrict__ bq, const float* __restrict__ bk, const float* __restrict__ bv,
    bf16* __restrict__ Qp, bf16* __restrict__ Kp, bf16* __restrict__ VpT) {
  __shared__ bf16 smem[17408];           // As(8192) + Bs(8192); reused as T[128][136] for z==2
  bf16* As = smem;
  bf16* Bs = smem + 8192;
  const int z = blockIdx.z;
  const bf16* A  = z == 0 ? Qb : (z == 1 ? Kb : Vb);
  const bf16* BT = z == 0 ? WqT : (z == 1 ? WkT : WvT);
  const float* bias = z == 0 ? bq : (z == 1 ? bk : bv);
  const int row0 = blockIdx.x * 128, col0 = blockIdx.y * 128;
  const int tid = threadIdx.x, lane = tid & 63, wave = tid >> 6;
  const int wq = wave >> 1, wn = wave & 1;
  f32x4 acc[4][4];
#pragma unroll
  for (int i = 0; i < 4; ++i)
#pragma unroll
    for (int j = 0; j < 4; ++j) acc[i][j] = (f32x4)0.0f;

  for (int k0 = 0; k0 < 1024; k0 += 64) {
#pragma unroll
    for (int it = 0; it < 4; ++it) {
      int boff = (it * 4 + wave) * 1024 + lane * 16;
      int r = boff >> 7, c = srcC(boff);
      gl16((const char*)A  + (size_t)(row0 + r) * 2048 + k0 * 2 + c, (char*)As + boff);
      gl16((const char*)BT + (size_t)(col0 + r) * 2048 + k0 * 2 + c, (char*)Bs + boff);
    }
    __syncthreads();
#pragma unroll
    for (int ks = 0; ks < 2; ++ks) {
      bf16x8 a[4], b[4];
#pragma unroll
      for (int i = 0; i < 4; ++i)
        a[i] = *(const bf16x8*)&As[swzE(wq * 64 + i * 16 + (lane & 15), ks * 32 + (lane >> 4) * 8)];
#pragma unroll
      for (int j = 0; j < 4; ++j)
        b[j] = *(const bf16x8*)&Bs[swzE(wn * 64 + j * 16 + (lane & 15), ks * 32 + (lane >> 4) * 8)];
#pragma unroll
      for (int i = 0; i < 4; ++i)
#pragma unroll
        for (int j = 0; j < 4; ++j) acc[i][j] = MF(a[i], b[j], acc[i][j]);
    }
    __syncthreads();
  }

  if (z < 2) {
    const float scl = (z == 0) ? 0.125f : 1.0f;
    bf16* C = z == 0 ? Qp : Kp;
#pragma unroll
    for (int i = 0; i < 4; ++i)
#pragma unroll
      for (int j = 0; j < 4; ++j) {
        int col = col0 + wn * 64 + j * 16 + (lane & 15);
        float bb = bias[col];
#pragma unroll
        for (int r = 0; r < 4; ++r) {
          int row = row0 + wq * 64 + i * 16 + (lane >> 4) * 4 + r;
          C[row * 1024 + col] = __float2bfloat16((acc[i][j][r] + bb) * scl);
        }
      }
  } else {
    // transpose epilogue: acc -> T[n_loc][s_loc] -> coalesced VpT writes
    bf16* T = smem;                       // [128][136] pitch: 272B rows, 16B-aligned
#pragma unroll
    for (int i = 0; i < 4; ++i)
#pragma unroll
      for (int j = 0; j < 4; ++j) {
        int nl = wn * 64 + j * 16 + (lane & 15);
        float bb = bias[col0 + nl];
#pragma unroll
        for (int r = 0; r < 4; ++r) {
          int sl = wq * 64 + i * 16 + (lane >> 4) * 4 + r;
          T[nl * 136 + sl] = __float2bfloat16(acc[i][j][r] + bb);
        }
      }
    __syncthreads();
    const int b = row0 >> 11, lr = row0 & 2047;
    const int nl = tid >> 1, half = tid & 1;
    const int n = col0 + nl;
    bf16* drow = VpT + ((size_t)(b * 16 + (n >> 6)) * 64 + (n & 63)) * 2048 + lr + half * 64;
#pragma unroll
    for (int k = 0; k < 8; ++k)
      *(short8v*)(drow + k * 8) = *(const short8v*)&T[nl * 136 + half * 64 + k * 8];
  }
}

// ---------- kernel 4: stats + V-scale. Z[bh][s] = sum_q exp(scores); VpT *= 1/Z ----------
__global__ __launch_bounds__(512, 4) void k_stats(
    const bf16* __restrict__ Qp, const bf16* __restrict__ Kp, bf16* __restrict__ VpT) {
  __shared__ bf16 Ks[128 * 64];
  __shared__ bf16 Qs[2][64 * 64];
  __shared__ float zs[128];
  const int id = blockIdx.x;
  const int sw = (id & 7) * 64 + (id >> 3);        // XCD swizzle (512 % 8 == 0 -> bijective)
  const int bh = sw >> 4, s0 = (sw & 15) * 128;
  const int b = bh >> 4, h = bh & 15;
  const char* Qrow = (const char*)(Qp + (size_t)(b * 2048) * 1024 + h * 64);
  const char* Krow = (const char*)(Kp + (size_t)(b * 2048) * 1024 + h * 64);
  const int tid = threadIdx.x, lane = tid & 63, wave = tid >> 6;

  // prologue: stage K s-tile (16KB) + Q chunk 0 (8KB)
  {
    int boff = tid * 16;
#pragma unroll
    for (int it = 0; it < 2; ++it) {
      int bo = boff + it * 8192;
      gl16(Krow + (size_t)(s0 + (bo >> 7)) * 2048 + srcC(bo), (char*)Ks + bo);
    }
    gl16(Qrow + (size_t)(boff >> 7) * 2048 + srcC(boff), (char*)Qs[0] + boff);
  }
  __syncthreads();
  bf16x8 afr[2];                                   // wave's 16 s-rows
#pragma unroll
  for (int ks = 0; ks < 2; ++ks)
    afr[ks] = *(const bf16x8*)&Ks[swzE(wave * 16 + (lane & 15), ks * 32 + (lane >> 4) * 8)];

  float zr[4] = {0.f, 0.f, 0.f, 0.f};
  for (int c = 0; c < 32; ++c) {
    const int p = c & 1;
    if (c < 31) {
      int boff = tid * 16;
      gl16(Qrow + (size_t)((c + 1) * 64 + (boff >> 7)) * 2048 + srcC(boff), (char*)Qs[p ^ 1] + boff);
    }
    f32x4 acc[4];
#pragma unroll
    for (int qf = 0; qf < 4; ++qf) acc[qf] = (f32x4)0.0f;
#pragma unroll
    for (int ks = 0; ks < 2; ++ks) {
      bf16x8 bfr[4];
#pragma unroll
      for (int qf = 0; qf < 4; ++qf)
        bfr[qf] = *(const bf16x8*)&Qs[p][swzE(qf * 16 + (lane & 15), ks * 32 + (lane >> 4) * 8)];
#pragma unroll
      for (int qf = 0; qf < 4; ++qf) acc[qf] = MF(afr[ks], bfr[qf], acc[qf]);
    }
#pragma unroll
    for (int qf = 0; qf < 4; ++qf)
#pragma unroll
      for (int r = 0; r < 4; ++r) zr[r] += __expf(acc[qf][r]);
    __syncthreads();
  }
#pragma unroll
  for (int m = 1; m <= 8; m <<= 1)
#pragma unroll
    for (int r = 0; r < 4; ++r) zr[r] += __shfl_xor(zr[r], m);
  if ((lane & 15) == 0) {
#pragma unroll
    for (int r = 0; r < 4; ++r) zs[wave * 16 + (lane >> 4) * 4 + r] = 1.0f / zr[r];
  }
  __syncthreads();
  // scale VpT[(bh*64+v)][s0..s0+127] by 1/Z[s]
  {
    const int v = tid >> 3, seg = tid & 7;
    bf16* base = VpT + (size_t)(bh * 64 + v) * 2048 + s0 + seg * 16;
    short8v x0 = *(const short8v*)base;
    short8v x1 = *(const short8v*)(base + 8);
    short8v o0, o1;
#pragma unroll
    for (int j = 0; j < 8; ++j) {
      o0[j] = bfbits(b2f(x0[j]) * zs[seg * 16 + j]);
      o1[j] = bfbits(b2f(x1[j]) * zs[seg * 16 + 8 + j]);
    }
    *(short8v*)base = o0;
    *(short8v*)(base + 8) = o1;
  }
}

// ---------- kernel 5: wV[q,v] = sum_s exp(scores[q,s]) * V'[s,v]  (1/Z folded into V') ----------
__global__ __launch_bounds__(512, 4) void k_attn_pv(
    const bf16* __restrict__ Qp, const bf16* __restrict__ Kp, const bf16* __restrict__ VpT,
    bf16* __restrict__ wV) {
  __shared__ bf16 QPs[128 * 64];                   // Q staging, then P tile (wave-private rows)
  __shared__ bf16 Ks[2][64 * 64];
  __shared__ bf16 Vs[2][64 * 64];
  const int id = blockIdx.x;
  const int sw = (id & 7) * 64 + (id >> 3);        // XCD swizzle: 4 heads' K/V per XCD-L2
  const int bh = sw >> 4, q0 = (sw & 15) * 128;
  const int b = bh >> 4, h = bh & 15;
  const char* Qrow = (const char*)(Qp + (size_t)(b * 2048) * 1024 + h * 64);
  const char* Krow = (const char*)(Kp + (size_t)(b * 2048) * 1024 + h * 64);
  const char* Vrow = (const char*)(VpT + (size_t)bh * 64 * 2048);
  const int tid = threadIdx.x, lane = tid & 63, wave = tid >> 6;

  // prologue: Q tile (16KB) + K/V chunk 0 (8KB each)
  {
    int boff = tid * 16;
#pragma unroll
    for (int it = 0; it < 2; ++it) {
      int bo = boff + it * 8192;
      gl16(Qrow + (size_t)(q0 + (bo >> 7)) * 2048 + srcC(bo), (char*)QPs + bo);
    }
    gl16(Krow + (size_t)(boff >> 7) * 2048 + srcC(boff), (char*)Ks[0] + boff);
    gl16(Vrow + (size_t)(boff >> 7) * 4096 + srcC(boff), (char*)Vs[0] + boff);
  }
  __syncthreads();
  bf16x8 aq[2];                                    // wave's 16 q-rows
#pragma unroll
  for (int ks = 0; ks < 2; ++ks)
    aq[ks] = *(const bf16x8*)&QPs[swzE(wave * 16 + (lane & 15), ks * 32 + (lane >> 4) * 8)];

  f32x4 acco[4];
#pragma unroll
  for (int vf = 0; vf < 4; ++vf) acco[vf] = (f32x4)0.0f;

  for (int c = 0; c < 32; ++c) {
    const int p = c & 1;
    if (c < 31) {                                  // stage next chunk (overlaps compute below)
      int boff = tid * 16;
      gl16(Krow + (size_t)((c + 1) * 64 + (boff >> 7)) * 2048 + srcC(boff), (char*)Ks[p ^ 1] + boff);
      gl16(Vrow + (size_t)(boff >> 7) * 4096 + (c + 1) * 128 + srcC(boff), (char*)Vs[p ^ 1] + boff);
    }
    // QK^T: C[16q][16s] per sf
    f32x4 sacc[4];
#pragma unroll
    for (int sf = 0; sf < 4; ++sf) sacc[sf] = (f32x4)0.0f;
#pragma unroll
    for (int ks = 0; ks < 2; ++ks) {
      bf16x8 bk_[4];
#pragma unroll
      for (int sf = 0; sf < 4; ++sf)
        bk_[sf] = *(const bf16x8*)&Ks[p][swzE(sf * 16 + (lane & 15), ks * 32 + (lane >> 4) * 8)];
#pragma unroll
      for (int sf = 0; sf < 4; ++sf) sacc[sf] = MF(aq[ks], bk_[sf], sacc[sf]);
    }
    // P = exp(scores) -> wave-private rows of QPs (swizzled)
#pragma unroll
    for (int sf = 0; sf < 4; ++sf) {
      int sl = sf * 16 + (lane & 15);
#pragma unroll
      for (int r = 0; r < 4; ++r) {
        int row = wave * 16 + (lane >> 4) * 4 + r;
        QPs[swzE(row, sl)] = __float2bfloat16(__expf(sacc[sf][r]));
      }
    }
    // PV accumulate
#pragma unroll
    for (int ks = 0; ks < 2; ++ks) {
      bf16x8 pa = *(const bf16x8*)&QPs[swzE(wave * 16 + (lane & 15), ks * 32 + (lane >> 4) * 8)];
      bf16x8 pb[4];
#pragma unroll
      for (int vf = 0; vf < 4; ++vf)
        pb[vf] = *(const bf16x8*)&Vs[p][swzE(vf * 16 + (lane & 15), ks * 32 + (lane >> 4) * 8)];
#pragma unroll
      for (int vf = 0; vf < 4; ++vf) acco[vf] = MF(pa, pb[vf], acco[vf]);
    }
    __syncthreads();
  }

  // epilogue: bounce acco through wave-private QPs rows, then coalesced stores
#pragma unroll
  for (int vf = 0; vf < 4; ++vf) {
    int v = vf * 16 + (lane & 15);
#pragma unroll
    for (int r = 0; r < 4; ++r)
      QPs[swzE(wave * 16 + (lane >> 4) * 4 + r, v)] = __float2bfloat16(acco[vf][r]);
  }
  {
    const int rr = wave * 16 + (lane >> 2);
    const int x = (rr & 7) << 3;
    short8v x0 = *(const short8v*)&QPs[rr * 64 + (((lane & 3) * 16) ^ x)];
    short8v x1 = *(const short8v*)&QPs[rr * 64 + (((lane & 3) * 16 + 8) ^ x)];
    bf16* dst = wV + ((size_t)bh * 2048 + q0 + rr) * 64 + (lane & 3) * 16;
    *(short8v*)dst = x0;
    *(short8v*)(dst + 8) = x1;
  }
}

// ---------- kernel 6: out[4096][1024] = wV_cat @ Wo + bo (fp32 out) ----------
__global__ __launch_bounds__(256) void k_out_gemm(
    const bf16* __restrict__ wV, const bf16* __restrict__ WoT, const float* __restrict__ bo,
    float* __restrict__ out) {
  __shared__ bf16 As[128 * 64], Bs[128 * 64];
  const int row0 = blockIdx.x * 128, col0 = blockIdx.y * 128;
  const int tid = threadIdx.x, lane = tid & 63, wave = tid >> 6;
  const int wq = wave >> 1, wn = wave & 1;
  const int b = row0 >> 11, lr = row0 & 2047;
  f32x4 acc[4][4];
#pragma unroll
  for (int i = 0; i < 4; ++i)
#pragma unroll
    for (int j = 0; j < 4; ++j) acc[i][j] = (f32x4)0.0f;

  for (int k0 = 0; k0 < 1024; k0 += 64) {
    const char* Abase = (const char*)(wV + ((size_t)(b * 16 + (k0 >> 6)) * 2048 + lr) * 64);
#pragma unroll
    for (int it = 0; it < 4; ++it) {
      int boff = (it * 4 + wave) * 1024 + lane * 16;
      int r = boff >> 7, c = srcC(boff);
      gl16(Abase + (size_t)r * 128 + c, (char*)As + boff);
      gl16((const char*)WoT + (size_t)(col0 + r) * 2048 + k0 * 2 + c, (char*)Bs + boff);
    }
    __syncthreads();
#pragma unroll
    for (int ks = 0; ks < 2; ++ks) {
      bf16x8 a[4], bb[4];
#pragma unroll
      for (int i = 0; i < 4; ++i)
        a[i] = *(const bf16x8*)&As[swzE(wq * 64 + i * 16 + (lane & 15), ks * 32 + (lane >> 4) * 8)];
#pragma unroll
      for (int j = 0; j < 4; ++j)
        bb[j] = *(const bf16x8*)&Bs[swzE(wn * 64 + j * 16 + (lane & 15), ks * 32 + (lane >> 4) * 8)];
#pragma unroll
      for (int i = 0; i < 4; ++i)
#pragma unroll
        for (int j = 0; j < 4; ++j) acc[i][j] = MF(a[i], bb[j], acc[i][j]);
    }
    __syncthreads();
  }
#pragma unroll
  for (int i = 0; i < 4; ++i)
#pragma unroll
    for (int j = 0; j < 4; ++j) {
      int col = col0 + wn * 64 + j * 16 + (lane & 15);
      float bb = bo[col];
#pragma unroll
      for (int r = 0; r < 4; ++r) {
        int row = row0 + wq * 64 + i * 16 + (lane >> 4) * 4 + r;
        out[row * 1024 + col] = acc[i][j][r] + bb;
      }
    }
}

extern "C" void kernel_launch(void* const* d_in, const int* in_sizes, int n_in,
                              void* d_out, int out_size, void* d_ws, size_t ws_size,
                              hipStream_t stream) {
  (void)in_sizes; (void)n_in; (void)out_size; (void)ws_size;
  const float* Q  = (const float*)d_in[0];
  const float* K  = (const float*)d_in[1];
  const float* V  = (const float*)d_in[2];
  const float* Wq = (const float*)d_in[3];
  const float* bq = (const float*)d_in[4];
  const float* Wk = (const float*)d_in[5];
  const float* bk = (const float*)d_in[6];
  const float* Wv = (const float*)d_in[7];
  const float* bv = (const float*)d_in[8];
  const float* Wo = (const float*)d_in[9];
  const float* bo = (const float*)d_in[10];

  char* ws = (char*)d_ws;
  bf16* Qb  = (bf16*)(ws);                     // 8 MB  [4096][1024]
  bf16* Kb  = (bf16*)(ws + (8u  << 20));       // 8 MB
  bf16* Vb  = (bf16*)(ws + (16u << 20));       // 8 MB
  bf16* WqT = (bf16*)(ws + (24u << 20));       // 2 MB  [1024 n][1024 m]
  bf16* WkT = (bf16*)(ws + (26u << 20));       // 2 MB
  bf16* WvT = (bf16*)(ws + (28u << 20));       // 2 MB
  bf16* WoT = (bf16*)(ws + (30u << 20));       // 2 MB
  bf16* Qp  = (bf16*)(ws + (32u << 20));       // 8 MB  [4096][1024] (pre-scaled by 0.125)
  bf16* Kp  = (bf16*)(ws + (40u << 20));       // 8 MB
  bf16* VpT = (bf16*)(ws + (48u << 20));       // 8 MB  [(bh*64+v)][2048 s] -> scaled by 1/Z in k_stats
  bf16* wVn = (bf16*)(ws + (56u << 20));       // 8 MB  [(bh*2048+l)][64 v]

  k_cvt_qkv <<<dim3(4096, 3), 256, 0, stream>>>(Q, K, V, Qb, Kb, Vb);
  k_prep_w  <<<dim3(16, 16, 4), 256, 0, stream>>>(Wq, Wk, Wv, Wo, WqT, WkT, WvT, WoT);
  k_proj_gemm<<<dim3(32, 8, 3), 256, 0, stream>>>(Qb, Kb, Vb, WqT, WkT, WvT, bq, bk, bv, Qp, Kp, VpT);
  k_stats   <<<512, 512, 0, stream>>>(Qp, Kp, VpT);
  k_attn_pv <<<512, 512, 0, stream>>>(Qp, Kp, VpT, wVn);
  k_out_gemm<<<dim3(32, 8), 256, 0, stream>>>(wVn, WoT, bo, (float*)d_out);
}

// Round 3
// 261.547 us; speedup vs baseline: 1.1710x; 1.0037x over previous
//
#include <hip/hip_runtime.h>
#include <hip/hip_bf16.h>

#define DEVI __device__ __forceinline__

typedef __hip_bfloat16 bf16;
typedef __attribute__((ext_vector_type(8))) __bf16 bf16x8;   // MFMA A/B operand (4 VGPRs)
typedef __attribute__((ext_vector_type(4))) float f32x4;     // 16x16 MFMA C/D
typedef __attribute__((ext_vector_type(16))) float f32x16;   // 32x32 MFMA C/D
typedef __attribute__((ext_vector_type(4))) short short4v;
typedef __attribute__((ext_vector_type(8))) short short8v;

// B=2, L=2048, DM=1024, H=16, DK=DV=64

DEVI short bfbits(float f) { bf16 h = __float2bfloat16(f); return *(short*)&h; }
DEVI float b2f(short s) { union { float f; unsigned u; } c; c.u = ((unsigned)(unsigned short)s) << 16; return c.f; }

DEVI void gl16(const void* g, void* l) {
  __builtin_amdgcn_global_load_lds((const __attribute__((address_space(1))) void*)g,
                                   (__attribute__((address_space(3))) void*)l, 16, 0, 0);
}

DEVI f32x4 MF(bf16x8 a, bf16x8 b, f32x4 c) {
  return __builtin_amdgcn_mfma_f32_16x16x32_bf16(a, b, c, 0, 0, 0);
}
DEVI f32x16 MF32(bf16x8 a, bf16x8 b, f32x16 c) {
  return __builtin_amdgcn_mfma_f32_32x32x16_bf16(a, b, c, 0, 0, 0);
}

DEVI unsigned cvtpk(float lo, float hi) {
  unsigned w;
  asm("v_cvt_pk_bf16_f32 %0, %1, %2" : "=v"(w) : "v"(lo), "v"(hi));
  return w;
}
DEVI void swap32(unsigned& a, unsigned& b) {
  asm volatile("v_permlane32_swap_b32 %0, %1" : "+v"(a), "+v"(b));
}
DEVI bf16x8 packB(unsigned w0, unsigned w1, unsigned w2, unsigned w3) {
  union { unsigned u[4]; bf16x8 v; } t;
  t.u[0] = w0; t.u[1] = w1; t.u[2] = w2; t.u[3] = w3;
  return t.v;
}

// XOR swizzle for 64-bf16 (128B) pitch LDS tiles.
DEVI int swzE(int row, int ec) { return row * 64 + (ec ^ ((row & 7) << 3)); }
// staging: for LDS linear byte offset boff, the GLOBAL source byte-col within the row.
DEVI int srcC(int boff) { return (boff & 127) ^ (((boff >> 7) & 7) << 4); }

// ---------- kernel 1: Q,K,V fp32 -> bf16 ----------
__global__ __launch_bounds__(256) void k_cvt_qkv(
    const float* __restrict__ Q, const float* __restrict__ K, const float* __restrict__ V,
    bf16* __restrict__ Qb, bf16* __restrict__ Kb, bf16* __restrict__ Vb) {
  const float* s = blockIdx.y == 0 ? Q : (blockIdx.y == 1 ? K : V);
  bf16* d = blockIdx.y == 0 ? Qb : (blockIdx.y == 1 ? Kb : Vb);
  int i = (blockIdx.x * 256 + threadIdx.x) * 4;
  float4 v = *(const float4*)(s + i);
  short4v o;
  o[0] = bfbits(v.x); o[1] = bfbits(v.y); o[2] = bfbits(v.z); o[3] = bfbits(v.w);
  *(short4v*)(d + i) = o;
}

// ---------- kernel 2: weight transpose + cvt ----------
__global__ __launch_bounds__(256) void k_prep_w(
    const float* __restrict__ Wq, const float* __restrict__ Wk, const float* __restrict__ Wv,
    const float* __restrict__ Wo,
    bf16* __restrict__ WqT, bf16* __restrict__ WkT, bf16* __restrict__ WvT,
    bf16* __restrict__ WoT) {
  __shared__ float t[64][65];
  const int z = blockIdx.z;
  const float* in; bf16* out; int ldin, ldout;
  if (z < 3) {
    const float* W = z == 0 ? Wq : (z == 1 ? Wk : Wv);
    bf16* O = z == 0 ? WqT : (z == 1 ? WkT : WvT);
    const int hh = blockIdx.y, m0 = blockIdx.x * 64;
    in = W + hh * 65536 + m0 * 64; ldin = 64;
    out = O + hh * 65536 + m0;     ldout = 1024;
  } else {
    const int r0 = blockIdx.x * 64, c0 = blockIdx.y * 64;
    in = Wo + r0 * 1024 + c0; ldin = 1024;
    out = WoT + c0 * 1024 + r0; ldout = 1024;
  }
  const int tx = threadIdx.x & 63, ty = threadIdx.x >> 6;
  for (int r = ty; r < 64; r += 4) t[r][tx] = in[r * ldin + tx];
  __syncthreads();
  for (int c = ty; c < 64; c += 4) out[c * ldout + tx] = __float2bfloat16(t[tx][c]);
}

// ---------- kernel 3: projections ----------
// z=0: Qp = (Q@Wq + bq) * 0.125  (1/sqrt(dk) folded in)
// z=1: Kp natural, z=2: Vp written TRANSPOSED per (b,h): VpT[(bh*64+v)][s] via LDS transpose
__global__ __launch_bounds__(256) void k_proj_gemm(
    const bf16* __restrict__ Qb, const bf16* __restrict__ Kb, const bf16* __restrict__ Vb,
    const bf16* __restrict__ WqT, const bf16* __restrict__ WkT, const bf16* __restrict__ WvT,
    const float* __restrict__ bq, const float* __restrict__ bk, const float* __restrict__ bv,
    bf16* __restrict__ Qp, bf16* __restrict__ Kp, bf16* __restrict__ VpT) {
  __shared__ bf16 smem[17408];           // As(8192) + Bs(8192); reused as T[128][136] for z==2
  bf16* As = smem;
  bf16* Bs = smem + 8192;
  const int z = blockIdx.z;
  const bf16* A  = z == 0 ? Qb : (z == 1 ? Kb : Vb);
  const bf16* BT = z == 0 ? WqT : (z == 1 ? WkT : WvT);
  const float* bias = z == 0 ? bq : (z == 1 ? bk : bv);
  const int row0 = blockIdx.x * 128, col0 = blockIdx.y * 128;
  const int tid = threadIdx.x, lane = tid & 63, wave = tid >> 6;
  const int wq = wave >> 1, wn = wave & 1;
  f32x4 acc[4][4];
#pragma unroll
  for (int i = 0; i < 4; ++i)
#pragma unroll
    for (int j = 0; j < 4; ++j) acc[i][j] = (f32x4)0.0f;

  for (int k0 = 0; k0 < 1024; k0 += 64) {
#pragma unroll
    for (int it = 0; it < 4; ++it) {
      int boff = (it * 4 + wave) * 1024 + lane * 16;
      int r = boff >> 7, c = srcC(boff);
      gl16((const char*)A  + (size_t)(row0 + r) * 2048 + k0 * 2 + c, (char*)As + boff);
      gl16((const char*)BT + (size_t)(col0 + r) * 2048 + k0 * 2 + c, (char*)Bs + boff);
    }
    __syncthreads();
#pragma unroll
    for (int ks = 0; ks < 2; ++ks) {
      bf16x8 a[4], b[4];
#pragma unroll
      for (int i = 0; i < 4; ++i)
        a[i] = *(const bf16x8*)&As[swzE(wq * 64 + i * 16 + (lane & 15), ks * 32 + (lane >> 4) * 8)];
#pragma unroll
      for (int j = 0; j < 4; ++j)
        b[j] = *(const bf16x8*)&Bs[swzE(wn * 64 + j * 16 + (lane & 15), ks * 32 + (lane >> 4) * 8)];
#pragma unroll
      for (int i = 0; i < 4; ++i)
#pragma unroll
        for (int j = 0; j < 4; ++j) acc[i][j] = MF(a[i], b[j], acc[i][j]);
    }
    __syncthreads();
  }

  if (z < 2) {
    const float scl = (z == 0) ? 0.125f : 1.0f;
    bf16* C = z == 0 ? Qp : Kp;
#pragma unroll
    for (int i = 0; i < 4; ++i)
#pragma unroll
      for (int j = 0; j < 4; ++j) {
        int col = col0 + wn * 64 + j * 16 + (lane & 15);
        float bb = bias[col];
#pragma unroll
        for (int r = 0; r < 4; ++r) {
          int row = row0 + wq * 64 + i * 16 + (lane >> 4) * 4 + r;
          C[row * 1024 + col] = __float2bfloat16((acc[i][j][r] + bb) * scl);
        }
      }
  } else {
    // transpose epilogue: acc -> T[n_loc][s_loc] -> coalesced VpT writes
    bf16* T = smem;                       // [128][136]
#pragma unroll
    for (int i = 0; i < 4; ++i)
#pragma unroll
      for (int j = 0; j < 4; ++j) {
        int nl = wn * 64 + j * 16 + (lane & 15);
        float bb = bias[col0 + nl];
#pragma unroll
        for (int r = 0; r < 4; ++r) {
          int sl = wq * 64 + i * 16 + (lane >> 4) * 4 + r;
          T[nl * 136 + sl] = __float2bfloat16(acc[i][j][r] + bb);
        }
      }
    __syncthreads();
    const int b = row0 >> 11, lr = row0 & 2047;
    const int nl = tid >> 1, half = tid & 1;
    const int n = col0 + nl;
    bf16* drow = VpT + ((size_t)(b * 16 + (n >> 6)) * 64 + (n & 63)) * 2048 + lr + half * 64;
#pragma unroll
    for (int k = 0; k < 8; ++k)
      *(short8v*)(drow + k * 8) = *(const short8v*)&T[nl * 136 + half * 64 + k * 8];
  }
}

// ---------- kernel 4: stats + V-scale ----------
// Wave owns 32 s-rows (K hoisted to regs). Streams Q chunks of 64.
// S^T tile = MF32(A=K_frag, B=Q_frag): row=s pattern, col=q=lane&31.
// Z[s] = sum_q exp(S^T[s][q]);  VpT[v][s-band] *= 1/Z[s].
__global__ __launch_bounds__(256, 2) void k_stats(
    const bf16* __restrict__ Qp, const bf16* __restrict__ Kp, bf16* __restrict__ VpT) {
  __shared__ bf16 Kband[128 * 64];       // 16KB
  __shared__ bf16 Qs[2][64 * 64];        // 16KB dbuf
  __shared__ float zs[128];
  const int id = blockIdx.x;
  const int sw = (id & 7) * 64 + (id >> 3);        // XCD swizzle (512 % 8 == 0 -> bijective)
  const int bh = sw >> 4, s0 = (sw & 15) * 128;
  const int b = bh >> 4, h = bh & 15;
  const char* Qrow = (const char*)(Qp + (size_t)(b * 2048) * 1024 + h * 64);
  const char* Krow = (const char*)(Kp + (size_t)(b * 2048) * 1024 + h * 64);
  const int tid = threadIdx.x, lane = tid & 63, wq = tid >> 6;
  const int ln31 = lane & 31, hf = lane >> 5;

  {
    int boff = tid * 16;
#pragma unroll
    for (int it = 0; it < 4; ++it) {
      int bo = boff + it * 4096;
      gl16(Krow + (size_t)(s0 + (bo >> 7)) * 2048 + srcC(bo), (char*)Kband + bo);
    }
    gl16(Qrow + (size_t)(boff >> 7) * 2048 + srcC(boff), (char*)Qs[0] + boff);
    gl16(Qrow + (size_t)((boff + 4096) >> 7) * 2048 + srcC(boff + 4096), (char*)Qs[0] + boff + 4096);
  }
  __syncthreads();
  bf16x8 kf[4];                                    // wave's 32 s-rows, hoisted
#pragma unroll
  for (int ks = 0; ks < 4; ++ks)
    kf[ks] = *(const bf16x8*)&Kband[swzE(wq * 32 + ln31, ks * 16 + hf * 8)];

  float zp[16];
#pragma unroll
  for (int r = 0; r < 16; ++r) zp[r] = 0.f;

  for (int c = 0; c < 32; ++c) {
    const int p = c & 1;
    if (c < 31) {
      int boff = tid * 16;
      gl16(Qrow + (size_t)((c + 1) * 64 + (boff >> 7)) * 2048 + srcC(boff), (char*)Qs[p ^ 1] + boff);
      gl16(Qrow + (size_t)((c + 1) * 64 + ((boff + 4096) >> 7)) * 2048 + srcC(boff + 4096),
           (char*)Qs[p ^ 1] + boff + 4096);
    }
    f32x16 sacc0 = (f32x16)0.0f, sacc1 = (f32x16)0.0f;
#pragma unroll
    for (int ks = 0; ks < 4; ++ks) {
      bf16x8 qf0 = *(const bf16x8*)&Qs[p][swzE(ln31, ks * 16 + hf * 8)];
      bf16x8 qf1 = *(const bf16x8*)&Qs[p][swzE(32 + ln31, ks * 16 + hf * 8)];
      sacc0 = MF32(kf[ks], qf0, sacc0);
      sacc1 = MF32(kf[ks], qf1, sacc1);
    }
#pragma unroll
    for (int r = 0; r < 16; ++r) zp[r] += __expf(sacc0[r]) + __expf(sacc1[r]);
    __syncthreads();
  }
#pragma unroll
  for (int m = 1; m <= 16; m <<= 1)
#pragma unroll
    for (int r = 0; r < 16; ++r) zp[r] += __shfl_xor(zp[r], m);
  if (ln31 == 0) {
#pragma unroll
    for (int r = 0; r < 16; ++r)
      zs[wq * 32 + (r & 3) + 8 * (r >> 2) + 4 * hf] = 1.0f / zp[r];
  }
  __syncthreads();
  // scale VpT[(bh*64+v)][s0..s0+127] by 1/Z[s]: 64 v x 128 s, 32 elems/thread
  {
    const int v = tid >> 2, sseg = (tid & 3) * 32;
    bf16* base = VpT + (size_t)(bh * 64 + v) * 2048 + s0 + sseg;
#pragma unroll
    for (int t = 0; t < 4; ++t) {
      short8v x = *(const short8v*)(base + t * 8);
      short8v o;
#pragma unroll
      for (int j = 0; j < 8; ++j) o[j] = bfbits(b2f(x[j]) * zs[sseg + t * 8 + j]);
      *(short8v*)(base + t * 8) = o;
    }
  }
}

// ---------- kernel 5: attention PV ----------
// Wave owns 32 q-rows (Q hoisted to regs). Streams K/V chunks of 64 s (dbuf).
// S^T = MF32(K, Q) -> P^T in regs -> cvt_pk+permlane32_swap -> PV B-frags.
// out^T = MF32(V^T, P^T-frags); 1/Z pre-folded into VpT by k_stats.
__global__ __launch_bounds__(256, 2) void k_attn_pv(
    const bf16* __restrict__ Qp, const bf16* __restrict__ Kp, const bf16* __restrict__ VpT,
    bf16* __restrict__ wV) {
  __shared__ bf16 Qs[128 * 64];          // 16KB (staged once)
  __shared__ bf16 Ks[2][64 * 64];        // 16KB dbuf
  __shared__ bf16 Vs[2][64 * 64];        // 16KB dbuf (VpT rows: [v][s])
  const int id = blockIdx.x;
  const int sw = (id & 7) * 64 + (id >> 3);        // XCD swizzle
  const int bh = sw >> 4, q0 = (sw & 15) * 128;
  const int b = bh >> 4, h = bh & 15;
  const char* Qrow = (const char*)(Qp + (size_t)(b * 2048) * 1024 + h * 64);
  const char* Krow = (const char*)(Kp + (size_t)(b * 2048) * 1024 + h * 64);
  const char* Vrow = (const char*)(VpT + (size_t)bh * 64 * 2048);
  const int tid = threadIdx.x, lane = tid & 63, wq = tid >> 6;
  const int ln31 = lane & 31, hf = lane >> 5;

  {
    int boff = tid * 16;
#pragma unroll
    for (int it = 0; it < 4; ++it) {
      int bo = boff + it * 4096;
      gl16(Qrow + (size_t)(q0 + (bo >> 7)) * 2048 + srcC(bo), (char*)Qs + bo);
    }
#pragma unroll
    for (int it = 0; it < 2; ++it) {
      int bo = boff + it * 4096;
      gl16(Krow + (size_t)(bo >> 7) * 2048 + srcC(bo), (char*)Ks[0] + bo);
      gl16(Vrow + (size_t)(bo >> 7) * 4096 + srcC(bo), (char*)Vs[0] + bo);
    }
  }
  __syncthreads();
  bf16x8 qf[4];                                    // wave's 32 q-rows, hoisted
#pragma unroll
  for (int ks = 0; ks < 4; ++ks)
    qf[ks] = *(const bf16x8*)&Qs[swzE(wq * 32 + ln31, ks * 16 + hf * 8)];

  f32x16 oacc0 = (f32x16)0.0f, oacc1 = (f32x16)0.0f;   // out^T v-blocks 0,1

  for (int c = 0; c < 32; ++c) {
    const int p = c & 1;
    if (c < 31) {                                  // stage next chunk before compute (T3)
      int boff = tid * 16;
#pragma unroll
      for (int it = 0; it < 2; ++it) {
        int bo = boff + it * 4096;
        gl16(Krow + (size_t)((c + 1) * 64 + (bo >> 7)) * 2048 + srcC(bo), (char*)Ks[p ^ 1] + bo);
        gl16(Vrow + (size_t)(bo >> 7) * 4096 + (c + 1) * 128 + srcC(bo), (char*)Vs[p ^ 1] + bo);
      }
    }
    // QK^T (swapped): sacc[sb] rows s = sb*32 + (r&3)+8*(r>>2)+4*hf, col q = wq*32+ln31
    f32x16 sacc0 = (f32x16)0.0f, sacc1 = (f32x16)0.0f;
#pragma unroll
    for (int ks = 0; ks < 4; ++ks) {
      bf16x8 kf0 = *(const bf16x8*)&Ks[p][swzE(ln31, ks * 16 + hf * 8)];
      bf16x8 kf1 = *(const bf16x8*)&Ks[p][swzE(32 + ln31, ks * 16 + hf * 8)];
      sacc0 = MF32(kf0, qf[ks], sacc0);
      sacc1 = MF32(kf1, qf[ks], sacc1);
    }
    // P^T = exp(S^T) -> PV B-frags in registers (cvt_pk + permlane32_swap)
    bf16x8 bfr[4];
#pragma unroll
    for (int sb = 0; sb < 2; ++sb) {
      const f32x16& sa = sb ? sacc1 : sacc0;
      float pz[16];
#pragma unroll
      for (int r = 0; r < 16; ++r) pz[r] = __expf(sa[r]);
#pragma unroll
      for (int half = 0; half < 2; ++half) {
        unsigned w0 = cvtpk(pz[half * 8 + 0], pz[half * 8 + 1]);
        unsigned w2 = cvtpk(pz[half * 8 + 4], pz[half * 8 + 5]);
        unsigned w1 = cvtpk(pz[half * 8 + 2], pz[half * 8 + 3]);
        unsigned w3 = cvtpk(pz[half * 8 + 6], pz[half * 8 + 7]);
        swap32(w0, w2);                            // -> e01, e45
        swap32(w1, w3);                            // -> e23, e67
        bfr[sb * 2 + half] = packB(w0, w1, w2, w3);
      }
    }
    // PV: A = V^T fragments from LDS, B = P^T fragments from regs
#pragma unroll
    for (int ks = 0; ks < 4; ++ks) {
      bf16x8 vf0 = *(const bf16x8*)&Vs[p][swzE(ln31, ks * 16 + hf * 8)];
      bf16x8 vf1 = *(const bf16x8*)&Vs[p][swzE(32 + ln31, ks * 16 + hf * 8)];
      oacc0 = MF32(vf0, bfr[ks], oacc0);
      oacc1 = MF32(vf1, bfr[ks], oacc1);
    }
    __syncthreads();
  }

  // epilogue: lane holds out[q][v] for q = q0+wq*32+ln31, v = vb*32+(r&3)+8*(r>>2)+4*hf
  {
    char* row = (char*)(wV + ((size_t)bh * 2048 + q0 + wq * 32 + ln31) * 64);
#pragma unroll
    for (int vb = 0; vb < 2; ++vb) {
      const f32x16& oa = vb ? oacc1 : oacc0;
#pragma unroll
      for (int qd = 0; qd < 4; ++qd) {
        uint2 w;
        w.x = cvtpk(oa[qd * 4 + 0], oa[qd * 4 + 1]);
        w.y = cvtpk(oa[qd * 4 + 2], oa[qd * 4 + 3]);
        *(uint2*)(row + vb * 64 + qd * 16 + hf * 8) = w;
      }
    }
  }
}

// ---------- kernel 6: out[4096][1024] = wV_cat @ Wo + bo (fp32 out) ----------
__global__ __launch_bounds__(256) void k_out_gemm(
    const bf16* __restrict__ wV, const bf16* __restrict__ WoT, const float* __restrict__ bo,
    float* __restrict__ out) {
  __shared__ bf16 As[128 * 64], Bs[128 * 64];
  const int row0 = blockIdx.x * 128, col0 = blockIdx.y * 128;
  const int tid = threadIdx.x, lane = tid & 63, wave = tid >> 6;
  const int wq = wave >> 1, wn = wave & 1;
  const int b = row0 >> 11, lr = row0 & 2047;
  f32x4 acc[4][4];
#pragma unroll
  for (int i = 0; i < 4; ++i)
#pragma unroll
    for (int j = 0; j < 4; ++j) acc[i][j] = (f32x4)0.0f;

  for (int k0 = 0; k0 < 1024; k0 += 64) {
    const char* Abase = (const char*)(wV + ((size_t)(b * 16 + (k0 >> 6)) * 2048 + lr) * 64);
#pragma unroll
    for (int it = 0; it < 4; ++it) {
      int boff = (it * 4 + wave) * 1024 + lane * 16;
      int r = boff >> 7, c = srcC(boff);
      gl16(Abase + (size_t)r * 128 + c, (char*)As + boff);
      gl16((const char*)WoT + (size_t)(col0 + r) * 2048 + k0 * 2 + c, (char*)Bs + boff);
    }
    __syncthreads();
#pragma unroll
    for (int ks = 0; ks < 2; ++ks) {
      bf16x8 a[4], bb[4];
#pragma unroll
      for (int i = 0; i < 4; ++i)
        a[i] = *(const bf16x8*)&As[swzE(wq * 64 + i * 16 + (lane & 15), ks * 32 + (lane >> 4) * 8)];
#pragma unroll
      for (int j = 0; j < 4; ++j)
        bb[j] = *(const bf16x8*)&Bs[swzE(wn * 64 + j * 16 + (lane & 15), ks * 32 + (lane >> 4) * 8)];
#pragma unroll
      for (int i = 0; i < 4; ++i)
#pragma unroll
        for (int j = 0; j < 4; ++j) acc[i][j] = MF(a[i], bb[j], acc[i][j]);
    }
    __syncthreads();
  }
#pragma unroll
  for (int i = 0; i < 4; ++i)
#pragma unroll
    for (int j = 0; j < 4; ++j) {
      int col = col0 + wn * 64 + j * 16 + (lane & 15);
      float bb = bo[col];
#pragma unroll
      for (int r = 0; r < 4; ++r) {
        int row = row0 + wq * 64 + i * 16 + (lane >> 4) * 4 + r;
        out[row * 1024 + col] = acc[i][j][r] + bb;
      }
    }
}

extern "C" void kernel_launch(void* const* d_in, const int* in_sizes, int n_in,
                              void* d_out, int out_size, void* d_ws, size_t ws_size,
                              hipStream_t stream) {
  (void)in_sizes; (void)n_in; (void)out_size; (void)ws_size;
  const float* Q  = (const float*)d_in[0];
  const float* K  = (const float*)d_in[1];
  const float* V  = (const float*)d_in[2];
  const float* Wq = (const float*)d_in[3];
  const float* bq = (const float*)d_in[4];
  const float* Wk = (const float*)d_in[5];
  const float* bk = (const float*)d_in[6];
  const float* Wv = (const float*)d_in[7];
  const float* bv = (const float*)d_in[8];
  const float* Wo = (const float*)d_in[9];
  const float* bo = (const float*)d_in[10];

  char* ws = (char*)d_ws;
  bf16* Qb  = (bf16*)(ws);                     // 8 MB  [4096][1024]
  bf16* Kb  = (bf16*)(ws + (8u  << 20));       // 8 MB
  bf16* Vb  = (bf16*)(ws + (16u << 20));       // 8 MB
  bf16* WqT = (bf16*)(ws + (24u << 20));       // 2 MB  [1024 n][1024 m]
  bf16* WkT = (bf16*)(ws + (26u << 20));       // 2 MB
  bf16* WvT = (bf16*)(ws + (28u << 20));       // 2 MB
  bf16* WoT = (bf16*)(ws + (30u << 20));       // 2 MB
  bf16* Qp  = (bf16*)(ws + (32u << 20));       // 8 MB  [4096][1024] (pre-scaled by 0.125)
  bf16* Kp  = (bf16*)(ws + (40u << 20));       // 8 MB
  bf16* VpT = (bf16*)(ws + (48u << 20));       // 8 MB  [(bh*64+v)][2048 s] -> scaled by 1/Z in k_stats
  bf16* wVn = (bf16*)(ws + (56u << 20));       // 8 MB  [(bh*2048+l)][64 v]

  k_cvt_qkv <<<dim3(4096, 3), 256, 0, stream>>>(Q, K, V, Qb, Kb, Vb);
  k_prep_w  <<<dim3(16, 16, 4), 256, 0, stream>>>(Wq, Wk, Wv, Wo, WqT, WkT, WvT, WoT);
  k_proj_gemm<<<dim3(32, 8, 3), 256, 0, stream>>>(Qb, Kb, Vb, WqT, WkT, WvT, bq, bk, bv, Qp, Kp, VpT);
  k_stats   <<<512, 256, 0, stream>>>(Qp, Kp, VpT);
  k_attn_pv <<<512, 256, 0, stream>>>(Qp, Kp, VpT, wVn);
  k_out_gemm<<<dim3(32, 8), 256, 0, stream>>>(wVn, WoT, bo, (float*)d_out);
}

// Round 5
// 258.917 us; speedup vs baseline: 1.1829x; 1.0102x over previous
//
#include <hip/hip_runtime.h>
#include <hip/hip_bf16.h>

#define DEVI __device__ __forceinline__

typedef __hip_bfloat16 bf16;
typedef __attribute__((ext_vector_type(8))) __bf16 bf16x8;   // MFMA A/B operand (4 VGPRs)
typedef __attribute__((ext_vector_type(4))) float f32x4;     // 16x16 MFMA C/D
typedef __attribute__((ext_vector_type(16))) float f32x16;   // 32x32 MFMA C/D
typedef __attribute__((ext_vector_type(4))) short short4v;
typedef __attribute__((ext_vector_type(8))) short short8v;

// B=2, L=2048, DM=1024, H=16, DK=DV=64

DEVI short bfbits(float f) { bf16 h = __float2bfloat16(f); return *(short*)&h; }
DEVI float b2f(short s) { union { float f; unsigned u; } c; c.u = ((unsigned)(unsigned short)s) << 16; return c.f; }

DEVI void gl16(const void* g, void* l) {
  __builtin_amdgcn_global_load_lds((const __attribute__((address_space(1))) void*)g,
                                   (__attribute__((address_space(3))) void*)l, 16, 0, 0);
}

DEVI f32x4 MF(bf16x8 a, bf16x8 b, f32x4 c) {
  return __builtin_amdgcn_mfma_f32_16x16x32_bf16(a, b, c, 0, 0, 0);
}
DEVI f32x16 MF32(bf16x8 a, bf16x8 b, f32x16 c) {
  return __builtin_amdgcn_mfma_f32_32x32x16_bf16(a, b, c, 0, 0, 0);
}

DEVI unsigned cvtpk(float lo, float hi) {
  unsigned w;
  asm("v_cvt_pk_bf16_f32 %0, %1, %2" : "=v"(w) : "v"(lo), "v"(hi));
  return w;
}
DEVI void swap32(unsigned& a, unsigned& b) {
  asm volatile("v_permlane32_swap_b32 %0, %1" : "+v"(a), "+v"(b));
}
DEVI bf16x8 packB(unsigned w0, unsigned w1, unsigned w2, unsigned w3) {
  union { unsigned u[4]; bf16x8 v; } t;
  t.u[0] = w0; t.u[1] = w1; t.u[2] = w2; t.u[3] = w3;
  return t.v;
}

// counted vmcnt (T4): wait until <= N vmem ops outstanding; loads stay in flight across barriers
#define WAITV(N) asm volatile("s_waitcnt vmcnt(" #N ")" ::: "memory")
#define SBAR __builtin_amdgcn_s_barrier()
#define SCHED0 __builtin_amdgcn_sched_barrier(0)

// XOR swizzle for 64-bf16 (128B) pitch LDS tiles.
DEVI int swzE(int row, int ec) { return row * 64 + (ec ^ ((row & 7) << 3)); }
// staging: for LDS linear byte offset boff, the GLOBAL source byte-col within the row.
DEVI int srcC(int boff) { return (boff & 127) ^ (((boff >> 7) & 7) << 4); }

// ---------- kernel 1: Q,K,V fp32 -> bf16 ----------
__global__ __launch_bounds__(256) void k_cvt_qkv(
    const float* __restrict__ Q, const float* __restrict__ K, const float* __restrict__ V,
    bf16* __restrict__ Qb, bf16* __restrict__ Kb, bf16* __restrict__ Vb) {
  const float* s = blockIdx.y == 0 ? Q : (blockIdx.y == 1 ? K : V);
  bf16* d = blockIdx.y == 0 ? Qb : (blockIdx.y == 1 ? Kb : Vb);
  int i = (blockIdx.x * 256 + threadIdx.x) * 4;
  float4 v = *(const float4*)(s + i);
  short4v o;
  o[0] = bfbits(v.x); o[1] = bfbits(v.y); o[2] = bfbits(v.z); o[3] = bfbits(v.w);
  *(short4v*)(d + i) = o;
}

// ---------- kernel 2: weight transpose + cvt ----------
__global__ __launch_bounds__(256) void k_prep_w(
    const float* __restrict__ Wq, const float* __restrict__ Wk, const float* __restrict__ Wv,
    const float* __restrict__ Wo,
    bf16* __restrict__ WqT, bf16* __restrict__ WkT, bf16* __restrict__ WvT,
    bf16* __restrict__ WoT) {
  __shared__ float t[64][65];
  const int z = blockIdx.z;
  const float* in; bf16* out; int ldin, ldout;
  if (z < 3) {
    const float* W = z == 0 ? Wq : (z == 1 ? Wk : Wv);
    bf16* O = z == 0 ? WqT : (z == 1 ? WkT : WvT);
    const int hh = blockIdx.y, m0 = blockIdx.x * 64;
    in = W + hh * 65536 + m0 * 64; ldin = 64;
    out = O + hh * 65536 + m0;     ldout = 1024;
  } else {
    const int r0 = blockIdx.x * 64, c0 = blockIdx.y * 64;
    in = Wo + r0 * 1024 + c0; ldin = 1024;
    out = WoT + c0 * 1024 + r0; ldout = 1024;
  }
  const int tx = threadIdx.x & 63, ty = threadIdx.x >> 6;
  for (int r = ty; r < 64; r += 4) t[r][tx] = in[r * ldin + tx];
  __syncthreads();
  for (int c = ty; c < 64; c += 4) out[c * ldout + tx] = __float2bfloat16(t[tx][c]);
}

// ---------- kernel 3: projections ----------
// z=0: Qp = (Q@Wq + bq) * 0.125  (1/sqrt(dk) folded in)
// z=1: Kp natural, z=2: Vp written TRANSPOSED per (b,h): VpT[(bh*64+v)][s] via LDS transpose
__global__ __launch_bounds__(256) void k_proj_gemm(
    const bf16* __restrict__ Qb, const bf16* __restrict__ Kb, const bf16* __restrict__ Vb,
    const bf16* __restrict__ WqT, const bf16* __restrict__ WkT, const bf16* __restrict__ WvT,
    const float* __restrict__ bq, const float* __restrict__ bk, const float* __restrict__ bv,
    bf16* __restrict__ Qp, bf16* __restrict__ Kp, bf16* __restrict__ VpT) {
  __shared__ bf16 smem[17408];           // As(8192) + Bs(8192); reused as T[128][136] for z==2
  bf16* As = smem;
  bf16* Bs = smem + 8192;
  const int z = blockIdx.z;
  const bf16* A  = z == 0 ? Qb : (z == 1 ? Kb : Vb);
  const bf16* BT = z == 0 ? WqT : (z == 1 ? WkT : WvT);
  const float* bias = z == 0 ? bq : (z == 1 ? bk : bv);
  const int row0 = blockIdx.x * 128, col0 = blockIdx.y * 128;
  const int tid = threadIdx.x, lane = tid & 63, wave = tid >> 6;
  const int wq = wave >> 1, wn = wave & 1;
  f32x4 acc[4][4];
#pragma unroll
  for (int i = 0; i < 4; ++i)
#pragma unroll
    for (int j = 0; j < 4; ++j) acc[i][j] = (f32x4)0.0f;

  for (int k0 = 0; k0 < 1024; k0 += 64) {
#pragma unroll
    for (int it = 0; it < 4; ++it) {
      int boff = (it * 4 + wave) * 1024 + lane * 16;
      int r = boff >> 7, c = srcC(boff);
      gl16((const char*)A  + (size_t)(row0 + r) * 2048 + k0 * 2 + c, (char*)As + boff);
      gl16((const char*)BT + (size_t)(col0 + r) * 2048 + k0 * 2 + c, (char*)Bs + boff);
    }
    __syncthreads();
#pragma unroll
    for (int ks = 0; ks < 2; ++ks) {
      bf16x8 a[4], b[4];
#pragma unroll
      for (int i = 0; i < 4; ++i)
        a[i] = *(const bf16x8*)&As[swzE(wq * 64 + i * 16 + (lane & 15), ks * 32 + (lane >> 4) * 8)];
#pragma unroll
      for (int j = 0; j < 4; ++j)
        b[j] = *(const bf16x8*)&Bs[swzE(wn * 64 + j * 16 + (lane & 15), ks * 32 + (lane >> 4) * 8)];
#pragma unroll
      for (int i = 0; i < 4; ++i)
#pragma unroll
        for (int j = 0; j < 4; ++j) acc[i][j] = MF(a[i], b[j], acc[i][j]);
    }
    __syncthreads();
  }

  if (z < 2) {
    const float scl = (z == 0) ? 0.125f : 1.0f;
    bf16* C = z == 0 ? Qp : Kp;
#pragma unroll
    for (int i = 0; i < 4; ++i)
#pragma unroll
      for (int j = 0; j < 4; ++j) {
        int col = col0 + wn * 64 + j * 16 + (lane & 15);
        float bb = bias[col];
#pragma unroll
        for (int r = 0; r < 4; ++r) {
          int row = row0 + wq * 64 + i * 16 + (lane >> 4) * 4 + r;
          C[row * 1024 + col] = __float2bfloat16((acc[i][j][r] + bb) * scl);
        }
      }
  } else {
    // transpose epilogue: acc -> T[n_loc][s_loc] -> coalesced VpT writes
    bf16* T = smem;                       // [128][136]
#pragma unroll
    for (int i = 0; i < 4; ++i)
#pragma unroll
      for (int j = 0; j < 4; ++j) {
        int nl = wn * 64 + j * 16 + (lane & 15);
        float bb = bias[col0 + nl];
#pragma unroll
        for (int r = 0; r < 4; ++r) {
          int sl = wq * 64 + i * 16 + (lane >> 4) * 4 + r;
          T[nl * 136 + sl] = __float2bfloat16(acc[i][j][r] + bb);
        }
      }
    __syncthreads();
    const int b = row0 >> 11, lr = row0 & 2047;
    const int nl = tid >> 1, half = tid & 1;
    const int n = col0 + nl;
    bf16* drow = VpT + ((size_t)(b * 16 + (n >> 6)) * 64 + (n & 63)) * 2048 + lr + half * 64;
#pragma unroll
    for (int k = 0; k < 8; ++k)
      *(short8v*)(drow + k * 8) = *(const short8v*)&T[nl * 136 + half * 64 + k * 8];
  }
}

// ---------- kernel 4: stats + V-scale (3-deep pipeline, counted vmcnt) ----------
// Wave owns 32 s-rows (K hoisted to regs). Streams Q chunks of 64 (2 gl16/thread/chunk).
// Z[s] = sum_q exp(S^T[s][q]);  VpT[v][s-band] *= 1/Z[s].
__global__ __launch_bounds__(256, 2) void k_stats(
    const bf16* __restrict__ Qp, const bf16* __restrict__ Kp, bf16* __restrict__ VpT) {
  __shared__ bf16 Kband[128 * 64];       // 16KB
  __shared__ bf16 Qs[3][64 * 64];        // 24KB, 3-deep
  __shared__ float zs[128];
  const int id = blockIdx.x;
  const int sw = (id & 7) * 64 + (id >> 3);        // XCD swizzle (512 % 8 == 0 -> bijective)
  const int bh = sw >> 4, s0 = (sw & 15) * 128;
  const int b = bh >> 4, h = bh & 15;
  const char* Qrow = (const char*)(Qp + (size_t)(b * 2048) * 1024 + h * 64);
  const char* Krow = (const char*)(Kp + (size_t)(b * 2048) * 1024 + h * 64);
  const int tid = threadIdx.x, lane = tid & 63, wq = tid >> 6;
  const int ln31 = lane & 31, hf = lane >> 5;
  const int boff = tid * 16;

  // prologue: K band (4 gl16) then Q chunks 0,1,2 (2 gl16 each)
#pragma unroll
  for (int it = 0; it < 4; ++it) {
    int bo = boff + it * 4096;
    gl16(Krow + (size_t)(s0 + (bo >> 7)) * 2048 + srcC(bo), (char*)Kband + bo);
  }
#pragma unroll
  for (int cc = 0; cc < 3; ++cc) {
    gl16(Qrow + (size_t)(cc * 64 + (boff >> 7)) * 2048 + srcC(boff), (char*)Qs[cc] + boff);
    gl16(Qrow + (size_t)(cc * 64 + ((boff + 4096) >> 7)) * 2048 + srcC(boff + 4096),
         (char*)Qs[cc] + boff + 4096);
  }
  WAITV(6); SBAR; SCHED0;                // K landed (Q0..2 may be in flight)
  bf16x8 kf[4];                          // wave's 32 s-rows, hoisted
#pragma unroll
  for (int ks = 0; ks < 4; ++ks)
    kf[ks] = *(const bf16x8*)&Kband[swzE(wq * 32 + ln31, ks * 16 + hf * 8)];

  float zp[16];
#pragma unroll
  for (int r = 0; r < 16; ++r) zp[r] = 0.f;

  for (int c = 0; c < 32; ++c) {
    const int p = c % 3;
    if (c <= 29) { WAITV(4); } else if (c == 30) { WAITV(2); } else { WAITV(0); }
    SBAR; SCHED0;
    f32x16 sacc0 = (f32x16)0.0f, sacc1 = (f32x16)0.0f;
#pragma unroll
    for (int ks = 0; ks < 4; ++ks) {
      bf16x8 qf0 = *(const bf16x8*)&Qs[p][swzE(ln31, ks * 16 + hf * 8)];
      bf16x8 qf1 = *(const bf16x8*)&Qs[p][swzE(32 + ln31, ks * 16 + hf * 8)];
      sacc0 = MF32(kf[ks], qf0, sacc0);
      sacc1 = MF32(kf[ks], qf1, sacc1);
    }
#pragma unroll
    for (int r = 0; r < 16; ++r) zp[r] += __expf(sacc0[r]) + __expf(sacc1[r]);
    SCHED0; SBAR;                        // all waves done reading Qs[p]
    if (c < 29) {
      gl16(Qrow + (size_t)((c + 3) * 64 + (boff >> 7)) * 2048 + srcC(boff), (char*)Qs[p] + boff);
      gl16(Qrow + (size_t)((c + 3) * 64 + ((boff + 4096) >> 7)) * 2048 + srcC(boff + 4096),
           (char*)Qs[p] + boff + 4096);
    }
  }
#pragma unroll
  for (int m = 1; m <= 16; m <<= 1)
#pragma unroll
    for (int r = 0; r < 16; ++r) zp[r] += __shfl_xor(zp[r], m);
  if (ln31 == 0) {
#pragma unroll
    for (int r = 0; r < 16; ++r)
      zs[wq * 32 + (r & 3) + 8 * (r >> 2) + 4 * hf] = 1.0f / zp[r];
  }
  __syncthreads();
  // scale VpT[(bh*64+v)][s0..s0+127] by 1/Z[s]: 64 v x 128 s, 32 elems/thread
  {
    const int v = tid >> 2, sseg = (tid & 3) * 32;
    bf16* base = VpT + (size_t)(bh * 64 + v) * 2048 + s0 + sseg;
#pragma unroll
    for (int t = 0; t < 4; ++t) {
      short8v x = *(const short8v*)(base + t * 8);
      short8v o;
#pragma unroll
      for (int j = 0; j < 8; ++j) o[j] = bfbits(b2f(x[j]) * zs[sseg + t * 8 + j]);
      *(short8v*)(base + t * 8) = o;
    }
  }
}

// ---------- kernel 5: attention PV (3-deep pipeline, counted vmcnt) ----------
// Wave owns 32 q-rows (Q hoisted to regs). Streams K/V chunks of 64 s (4 gl16/thread/chunk).
// S^T = MF32(K, Q) -> P^T in regs -> cvt_pk+permlane32_swap -> PV B-frags.
// out^T = MF32(V^T, P^T-frags); 1/Z pre-folded into VpT by k_stats.
__global__ __launch_bounds__(256, 2) void k_attn_pv(
    const bf16* __restrict__ Qp, const bf16* __restrict__ Kp, const bf16* __restrict__ VpT,
    bf16* __restrict__ wV) {
  __shared__ bf16 Qs[128 * 64];          // 16KB (staged once)
  __shared__ bf16 Ks[3][64 * 64];        // 24KB, 3-deep
  __shared__ bf16 Vs[3][64 * 64];        // 24KB, 3-deep (VpT rows: [v][s])
  const int id = blockIdx.x;
  const int sw = (id & 7) * 64 + (id >> 3);        // XCD swizzle
  const int bh = sw >> 4, q0 = (sw & 15) * 128;
  const int b = bh >> 4, h = bh & 15;
  const char* Qrow = (const char*)(Qp + (size_t)(b * 2048) * 1024 + h * 64);
  const char* Krow = (const char*)(Kp + (size_t)(b * 2048) * 1024 + h * 64);
  const char* Vrow = (const char*)(VpT + (size_t)bh * 64 * 2048);
  const int tid = threadIdx.x, lane = tid & 63, wq = tid >> 6;
  const int ln31 = lane & 31, hf = lane >> 5;
  const int boff = tid * 16;

  // prologue: Q tile (4 gl16) then K/V chunks 0,1,2 (4 gl16 each)
#pragma unroll
  for (int it = 0; it < 4; ++it) {
    int bo = boff + it * 4096;
    gl16(Qrow + (size_t)(q0 + (bo >> 7)) * 2048 + srcC(bo), (char*)Qs + bo);
  }
#pragma unroll
  for (int cc = 0; cc < 3; ++cc) {
#pragma unroll
    for (int it = 0; it < 2; ++it) {
      int bo = boff + it * 4096;
      gl16(Krow + (size_t)(cc * 64 + (bo >> 7)) * 2048 + srcC(bo), (char*)Ks[cc] + bo);
      gl16(Vrow + (size_t)(bo >> 7) * 4096 + cc * 128 + srcC(bo), (char*)Vs[cc] + bo);
    }
  }
  WAITV(12); SBAR; SCHED0;               // Q landed (chunks 0..2 may be in flight)
  bf16x8 qf[4];                          // wave's 32 q-rows, hoisted
#pragma unroll
  for (int ks = 0; ks < 4; ++ks)
    qf[ks] = *(const bf16x8*)&Qs[swzE(wq * 32 + ln31, ks * 16 + hf * 8)];

  f32x16 oacc0 = (f32x16)0.0f, oacc1 = (f32x16)0.0f;   // out^T v-blocks 0,1

  for (int c = 0; c < 32; ++c) {
    const int p = c % 3;
    if (c <= 29) { WAITV(8); } else if (c == 30) { WAITV(4); } else { WAITV(0); }
    SBAR; SCHED0;
    // QK^T (swapped): sacc[sb] rows s = sb*32 + (r&3)+8*(r>>2)+4*hf, col q = wq*32+ln31
    f32x16 sacc0 = (f32x16)0.0f, sacc1 = (f32x16)0.0f;
#pragma unroll
    for (int ks = 0; ks < 4; ++ks) {
      bf16x8 kf0 = *(const bf16x8*)&Ks[p][swzE(ln31, ks * 16 + hf * 8)];
      bf16x8 kf1 = *(const bf16x8*)&Ks[p][swzE(32 + ln31, ks * 16 + hf * 8)];
      sacc0 = MF32(kf0, qf[ks], sacc0);
      sacc1 = MF32(kf1, qf[ks], sacc1);
    }
    // P^T = exp(S^T) -> PV B-frags in registers (cvt_pk + permlane32_swap)
    bf16x8 bfr[4];
#pragma unroll
    for (int sb = 0; sb < 2; ++sb) {
      const f32x16& sa = sb ? sacc1 : sacc0;
      float pz[16];
#pragma unroll
      for (int r = 0; r < 16; ++r) pz[r] = __expf(sa[r]);
#pragma unroll
      for (int half = 0; half < 2; ++half) {
        unsigned w0 = cvtpk(pz[half * 8 + 0], pz[half * 8 + 1]);
        unsigned w2 = cvtpk(pz[half * 8 + 4], pz[half * 8 + 5]);
        unsigned w1 = cvtpk(pz[half * 8 + 2], pz[half * 8 + 3]);
        unsigned w3 = cvtpk(pz[half * 8 + 6], pz[half * 8 + 7]);
        swap32(w0, w2);                            // -> e01, e45
        swap32(w1, w3);                            // -> e23, e67
        bfr[sb * 2 + half] = packB(w0, w1, w2, w3);
      }
    }
    // PV: A = V^T fragments from LDS, B = P^T fragments from regs
#pragma unroll
    for (int ks = 0; ks < 4; ++ks) {
      bf16x8 vf0 = *(const bf16x8*)&Vs[p][swzE(ln31, ks * 16 + hf * 8)];
      bf16x8 vf1 = *(const bf16x8*)&Vs[p][swzE(32 + ln31, ks * 16 + hf * 8)];
      oacc0 = MF32(vf0, bfr[ks], oacc0);
      oacc1 = MF32(vf1, bfr[ks], oacc1);
    }
    SCHED0; SBAR;                        // all waves done reading Ks[p]/Vs[p]
    if (c < 29) {
#pragma unroll
      for (int it = 0; it < 2; ++it) {
        int bo = boff + it * 4096;
        gl16(Krow + (size_t)((c + 3) * 64 + (bo >> 7)) * 2048 + srcC(bo), (char*)Ks[p] + bo);
        gl16(Vrow + (size_t)(bo >> 7) * 4096 + (c + 3) * 128 + srcC(bo), (char*)Vs[p] + bo);
      }
    }
  }

  // epilogue: lane holds out[q][v] for q = q0+wq*32+ln31, v = vb*32+(r&3)+8*(r>>2)+4*hf
  {
    char* row = (char*)(wV + ((size_t)bh * 2048 + q0 + wq * 32 + ln31) * 64);
#pragma unroll
    for (int vb = 0; vb < 2; ++vb) {
      const f32x16& oa = vb ? oacc1 : oacc0;
#pragma unroll
      for (int qd = 0; qd < 4; ++qd) {
        uint2 w;
        w.x = cvtpk(oa[qd * 4 + 0], oa[qd * 4 + 1]);
        w.y = cvtpk(oa[qd * 4 + 2], oa[qd * 4 + 3]);
        *(uint2*)(row + vb * 64 + qd * 16 + hf * 8) = w;
      }
    }
  }
}

// ---------- kernel 6: out[4096][1024] = wV_cat @ Wo + bo (fp32 out) ----------
__global__ __launch_bounds__(256) void k_out_gemm(
    const bf16* __restrict__ wV, const bf16* __restrict__ WoT, const float* __restrict__ bo,
    float* __restrict__ out) {
  __shared__ bf16 As[128 * 64], Bs[128 * 64];
  const int row0 = blockIdx.x * 128, col0 = blockIdx.y * 128;
  const int tid = threadIdx.x, lane = tid & 63, wave = tid >> 6;
  const int wq = wave >> 1, wn = wave & 1;
  const int b = row0 >> 11, lr = row0 & 2047;
  f32x4 acc[4][4];
#pragma unroll
  for (int i = 0; i < 4; ++i)
#pragma unroll
    for (int j = 0; j < 4; ++j) acc[i][j] = (f32x4)0.0f;

  for (int k0 = 0; k0 < 1024; k0 += 64) {
    const char* Abase = (const char*)(wV + ((size_t)(b * 16 + (k0 >> 6)) * 2048 + lr) * 64);
#pragma unroll
    for (int it = 0; it < 4; ++it) {
      int boff = (it * 4 + wave) * 1024 + lane * 16;
      int r = boff >> 7, c = srcC(boff);
      gl16(Abase + (size_t)r * 128 + c, (char*)As + boff);
      gl16((const char*)WoT + (size_t)(col0 + r) * 2048 + k0 * 2 + c, (char*)Bs + boff);
    }
    __syncthreads();
#pragma unroll
    for (int ks = 0; ks < 2; ++ks) {
      bf16x8 a[4], bb[4];
#pragma unroll
      for (int i = 0; i < 4; ++i)
        a[i] = *(const bf16x8*)&As[swzE(wq * 64 + i * 16 + (lane & 15), ks * 32 + (lane >> 4) * 8)];
#pragma unroll
      for (int j = 0; j < 4; ++j)
        bb[j] = *(const bf16x8*)&Bs[swzE(wn * 64 + j * 16 + (lane & 15), ks * 32 + (lane >> 4) * 8)];
#pragma unroll
      for (int i = 0; i < 4; ++i)
#pragma unroll
        for (int j = 0; j < 4; ++j) acc[i][j] = MF(a[i], bb[j], acc[i][j]);
    }
    __syncthreads();
  }
#pragma unroll
  for (int i = 0; i < 4; ++i)
#pragma unroll
    for (int j = 0; j < 4; ++j) {
      int col = col0 + wn * 64 + j * 16 + (lane & 15);
      float bb = bo[col];
#pragma unroll
      for (int r = 0; r < 4; ++r) {
        int row = row0 + wq * 64 + i * 16 + (lane >> 4) * 4 + r;
        out[row * 1024 + col] = acc[i][j][r] + bb;
      }
    }
}

extern "C" void kernel_launch(void* const* d_in, const int* in_sizes, int n_in,
                              void* d_out, int out_size, void* d_ws, size_t ws_size,
                              hipStream_t stream) {
  (void)in_sizes; (void)n_in; (void)out_size; (void)ws_size;
  const float* Q  = (const float*)d_in[0];
  const float* K  = (const float*)d_in[1];
  const float* V  = (const float*)d_in[2];
  const float* Wq = (const float*)d_in[3];
  const float* bq = (const float*)d_in[4];
  const float* Wk = (const float*)d_in[5];
  const float* bk = (const float*)d_in[6];
  const float* Wv = (const float*)d_in[7];
  const float* bv = (const float*)d_in[8];
  const float* Wo = (const float*)d_in[9];
  const float* bo = (const float*)d_in[10];

  char* ws = (char*)d_ws;
  bf16* Qb  = (bf16*)(ws);                     // 8 MB  [4096][1024]
  bf16* Kb  = (bf16*)(ws + (8u  << 20));       // 8 MB
  bf16* Vb  = (bf16*)(ws + (16u << 20));       // 8 MB
  bf16* WqT = (bf16*)(ws + (24u << 20));       // 2 MB  [1024 n][1024 m]
  bf16* WkT = (bf16*)(ws + (26u << 20));       // 2 MB
  bf16* WvT = (bf16*)(ws + (28u << 20));       // 2 MB
  bf16* WoT = (bf16*)(ws + (30u << 20));       // 2 MB
  bf16* Qp  = (bf16*)(ws + (32u << 20));       // 8 MB  [4096][1024] (pre-scaled by 0.125)
  bf16* Kp  = (bf16*)(ws + (40u << 20));       // 8 MB
  bf16* VpT = (bf16*)(ws + (48u << 20));       // 8 MB  [(bh*64+v)][2048 s] -> scaled by 1/Z in k_stats
  bf16* wVn = (bf16*)(ws + (56u << 20));       // 8 MB  [(bh*2048+l)][64 v]

  k_cvt_qkv <<<dim3(4096, 3), 256, 0, stream>>>(Q, K, V, Qb, Kb, Vb);
  k_prep_w  <<<dim3(16, 16, 4), 256, 0, stream>>>(Wq, Wk, Wv, Wo, WqT, WkT, WvT, WoT);
  k_proj_gemm<<<dim3(32, 8, 3), 256, 0, stream>>>(Qb, Kb, Vb, WqT, WkT, WvT, bq, bk, bv, Qp, Kp, VpT);
  k_stats   <<<512, 256, 0, stream>>>(Qp, Kp, VpT);
  k_attn_pv <<<512, 256, 0, stream>>>(Qp, Kp, VpT, wVn);
  k_out_gemm<<<dim3(32, 8), 256, 0, stream>>>(wVn, WoT, bo, (float*)d_out);
}